// Round 13
// baseline (358.846 us; speedup 1.0000x reference)
//
#include <hip/hip_runtime.h>

#define N_NODES 100000
#define N_EDGES 600000
#define N_GRAPHS 512

typedef __attribute__((ext_vector_type(8))) short short8;
typedef __attribute__((ext_vector_type(4))) float floatx4;

__device__ __forceinline__ unsigned short f2bf(float f) {   // RNE f32 -> bf16
    unsigned int u = __float_as_uint(f);
    u += 0x7FFFu + ((u >> 16) & 1u);
    return (unsigned short)(u >> 16);
}
__device__ __forceinline__ float bf_lo(unsigned int u) { return __uint_as_float(u << 16); }
__device__ __forceinline__ float bf_hi(unsigned int u) { return __uint_as_float(u & 0xFFFF0000u); }

__device__ __forceinline__ void fma8(float* a, short8 v, float n) {
    union { short8 s; unsigned int u[4]; } c; c.s = v;
    #pragma unroll
    for (int j = 0; j < 4; ++j) {
        a[2 * j]     = fmaf(bf_lo(c.u[j]), n, a[2 * j]);
        a[2 * j + 1] = fmaf(bf_hi(c.u[j]), n, a[2 * j + 1]);
    }
}
__device__ __forceinline__ void init8(float* a, short8 v, float s) {
    union { short8 s; unsigned int u[4]; } c; c.s = v;
    #pragma unroll
    for (int j = 0; j < 4; ++j) {
        a[2 * j]     = bf_lo(c.u[j]) * s;
        a[2 * j + 1] = bf_hi(c.u[j]) * s;
    }
}
__device__ __forceinline__ short8 pack8(const float* a) {
    short8 r;
    #pragma unroll
    for (int j = 0; j < 8; ++j) r[j] = (short)f2bf(a[j]);
    return r;
}

// ---------------------------------------------------------------- degree hist (cnt zeroed by memset)
__global__ void k_hist(const int* __restrict__ dst, int* cnt) {
    int e = blockIdx.x * 256 + threadIdx.x;
    if (e < N_EDGES) atomicAdd(&cnt[dst[e]], 1);
}

// ---------------------------------------------------------------- scan1: block sums of cnt
__global__ void k_scan1(const int* __restrict__ cnt, int* __restrict__ part) {
    __shared__ int s[256];
    int t = threadIdx.x;
    int i = blockIdx.x * 256 + t;
    int v = (i < N_NODES) ? cnt[i] : 0;
    s[t] = v; __syncthreads();
    for (int off = 128; off > 0; off >>= 1) {
        if (t < off) s[t] += s[t + off];
        __syncthreads();
    }
    if (t == 0) part[blockIdx.x] = s[0];
}

// ---------------------------------------------------------------- scan3: computes its own base from part[]
__global__ void k_scan3(const int* __restrict__ cnt, const int* __restrict__ part,
                        int* __restrict__ row_ptr, int* __restrict__ cursor,
                        float* __restrict__ dis) {
    __shared__ int s[256];
    __shared__ int pbaseS;
    int t = threadIdx.x;
    int psum = 0;
    for (int k = t; k < blockIdx.x; k += 256) psum += part[k];
    s[t] = psum; __syncthreads();
    for (int off = 128; off > 0; off >>= 1) {
        if (t < off) s[t] += s[t + off];
        __syncthreads();
    }
    if (t == 0) pbaseS = s[0];
    __syncthreads();
    int pbase = pbaseS;
    __syncthreads();
    int i = blockIdx.x * 256 + t;
    int v = (i < N_NODES) ? cnt[i] : 0;
    s[t] = v; __syncthreads();
    for (int off = 1; off < 256; off <<= 1) {
        int u = (t >= off) ? s[t - off] : 0;
        __syncthreads();
        s[t] += u;
        __syncthreads();
    }
    int ex = s[t] - v + pbase;
    if (i < N_NODES) {
        row_ptr[i] = ex; cursor[i] = ex;
        dis[i] = 1.0f / sqrtf((float)(v + 1));   // deg includes self-loop
    }
    if (blockIdx.x == 0 && t == 0) row_ptr[N_NODES] = N_EDGES;
}

// ---------------------------------------------------------------- CSR scatter
__global__ void k_scatter(const int* __restrict__ src, const int* __restrict__ dst,
                          const float* __restrict__ dis, int* __restrict__ cursor,
                          int* __restrict__ csr_src, float* __restrict__ csr_norm) {
    int e = blockIdx.x * 256 + threadIdx.x;
    if (e >= N_EDGES) return;
    int s = src[e], d = dst[e];
    int pos = atomicAdd(&cursor[d], 1);
    csr_src[pos] = s;
    csr_norm[pos] = dis[s] * dis[d];
}

// ---------------------------------------------------------------- pack W2/W3 to B-frag order (device fn)
__device__ __forceinline__ void pack_one(const float* __restrict__ W, unsigned short* __restrict__ out,
                                         int idx, int N) {
    int lane = idx & 63;
    int ks = (idx >> 6) & 3;
    int ct = idx >> 8;
    int n = ct * 16 + (lane & 15);
    int kbase = ks * 32 + (lane >> 4) * 8;
    #pragma unroll
    for (int j = 0; j < 8; ++j)
        out[(size_t)idx * 8 + j] = f2bf(W[(size_t)(kbase + j) * N + n]);
}

// ---------------------------------------------------------------- layer 1 fused: agg(F=3) + GEMM 3->128 + b1 + relu -> bf16
// 4 nodes/wave: 16 lanes per node. Last 12 blocks instead pack W2/W3 (fused dispatch).
#define NB1 6250
__global__ __launch_bounds__(256) void k_node1(const float* __restrict__ x,
                                               const float* __restrict__ dis,
                                               const int* __restrict__ row_ptr,
                                               const int* __restrict__ csr_src,
                                               const float* __restrict__ csr_norm,
                                               const float* __restrict__ W1,
                                               const float* __restrict__ b1,
                                               unsigned short* __restrict__ out,
                                               const float* __restrict__ W2,
                                               const float* __restrict__ W3,
                                               unsigned short* __restrict__ Wp2,
                                               unsigned short* __restrict__ Wp3) {
    int tid = threadIdx.x;
    if (blockIdx.x >= NB1) {                         // weight-pack role
        int idx = (blockIdx.x - NB1) * 256 + tid;    // 12 blocks = 3072
        if (idx < 2048) pack_one(W2, Wp2, idx, 128);
        else if (idx < 3072) pack_one(W3, Wp3, idx - 2048, 64);
        return;
    }
    __shared__ float Ws[384];
    __shared__ float bs[128];
    for (int i = tid; i < 384; i += 256) Ws[i] = W1[i];
    if (tid < 128) bs[tid] = b1[tid];
    __syncthreads();
    int gw = (blockIdx.x * 256 + tid) >> 6;          // 25000 waves
    int lane = tid & 63;
    int sub = lane >> 4, l16 = lane & 15;
    int node = gw * 4 + sub;                         // 100000 = 25000*4 exact
    int beg = row_ptr[node], end = row_ptr[node + 1];
    float p0 = 0.f, p1 = 0.f, p2 = 0.f;
    for (int e = beg + l16; e < end; e += 16) {
        int s = csr_src[e];
        float n = csr_norm[e];
        p0 = fmaf(x[s * 3 + 0], n, p0);
        p1 = fmaf(x[s * 3 + 1], n, p1);
        p2 = fmaf(x[s * 3 + 2], n, p2);
    }
    #pragma unroll
    for (int m = 8; m > 0; m >>= 1) {                // butterfly within 16-lane group
        p0 += __shfl_xor(p0, m, 64);
        p1 += __shfl_xor(p1, m, 64);
        p2 += __shfl_xor(p2, m, 64);
    }
    float d = dis[node], s2 = d * d;
    float a0 = fmaf(x[node * 3 + 0], s2, p0);
    float a1 = fmaf(x[node * 3 + 1], s2, p1);
    float a2 = fmaf(x[node * 3 + 2], s2, p2);
    int f = l16 * 8;
    float v[8];
    #pragma unroll
    for (int j = 0; j < 8; ++j)
        v[j] = fmaxf(bs[f + j] + a0 * Ws[f + j] + a1 * Ws[128 + f + j] + a2 * Ws[256 + f + j], 0.f);
    *(short8*)(out + (size_t)node * 128 + f) = pack8(v);
}

// ---------------------------------------------------------------- layers 2+3 fused, 16-node blocks:
// each wave aggregates 4 nodes in ONE gather round (16 lanes/node, 8 feats/lane) -> low VGPR, high occupancy.
// -> LDS -> MFMA GEMM2 (+b2, relu) -> LDS -> MFMA GEMM3 -> Q2b.  100000 = 6250 * 16 exact.
__global__ __launch_bounds__(256) void k_layer23(const unsigned short* __restrict__ h1,
                                                 const float* __restrict__ dis,
                                                 const int* __restrict__ row_ptr,
                                                 const int* __restrict__ csr_src,
                                                 const float* __restrict__ csr_norm,
                                                 const unsigned short* __restrict__ Wp2,
                                                 const float* __restrict__ b2,
                                                 const unsigned short* __restrict__ Wp3,
                                                 unsigned short* __restrict__ Q2b) {
    __shared__ unsigned short Asb[16][136];   // aggregated h1 tile
    __shared__ unsigned short Hsb[16][136];   // h2 tile
    int tid = threadIdx.x;
    int wave = tid >> 6, lane = tid & 63;
    int quad = lane >> 4, m16 = lane & 15;
    int base = blockIdx.x * 16;

    // ---- phase 1: 4 nodes per wave, all 8 gathers in flight, one latency round (common case)
    {
        int sub = lane >> 4, l16 = lane & 15;
        int r = wave * 4 + sub;
        int node = base + r;
        int beg = row_ptr[node], end = row_ptr[node + 1];
        int idx[8]; float nn[8];
        #pragma unroll
        for (int u = 0; u < 8; ++u) {
            int ee = beg + u; int cl = ee < end ? ee : end - 1;
            idx[u] = csr_src[cl]; nn[u] = ee < end ? csr_norm[cl] : 0.0f;
        }
        float d = dis[node];
        short8 self = *(const short8*)(h1 + (size_t)node * 128 + l16 * 8);
        short8 g[8];
        #pragma unroll
        for (int u = 0; u < 8; ++u)
            g[u] = *(const short8*)(h1 + (size_t)idx[u] * 128 + l16 * 8);
        float a[8];
        init8(a, self, d * d);
        #pragma unroll
        for (int u = 0; u < 8; ++u) fma8(a, g[u], nn[u]);
        for (int e = beg + 8; e < end; e += 8) {       // rare remainder (P(deg>8)~15%)
            int idx2[8]; float nn2[8];
            #pragma unroll
            for (int u = 0; u < 8; ++u) {
                int ee = e + u; int cl = ee < end ? ee : end - 1;
                idx2[u] = csr_src[cl]; nn2[u] = ee < end ? csr_norm[cl] : 0.0f;
            }
            short8 g2[8];
            #pragma unroll
            for (int u = 0; u < 8; ++u)
                g2[u] = *(const short8*)(h1 + (size_t)idx2[u] * 128 + l16 * 8);
            #pragma unroll
            for (int u = 0; u < 8; ++u) fma8(a, g2[u], nn2[u]);
        }
        *(short8*)(&Asb[r][l16 * 8]) = pack8(a);
    }
    __syncthreads();

    // ---- phase 2: 16x128 = Asb(16x128) @ Wp2(128x128), +b2, relu -> Hsb
    // wave computes column tiles {2*wave, 2*wave+1}
    {
        short8 af[4];
        #pragma unroll
        for (int ks = 0; ks < 4; ++ks)
            af[ks] = *(const short8*)(&Asb[m16][ks * 32 + quad * 8]);
        floatx4 acc[2];
        acc[0] = (floatx4){0.f, 0.f, 0.f, 0.f};
        acc[1] = (floatx4){0.f, 0.f, 0.f, 0.f};
        #pragma unroll
        for (int c = 0; c < 2; ++c) {
            int gct = wave * 2 + c;
            #pragma unroll
            for (int ks = 0; ks < 4; ++ks) {
                short8 bf = *(const short8*)(Wp2 + ((size_t)(gct * 4 + ks) * 64 + lane) * 8);
                acc[c] = __builtin_amdgcn_mfma_f32_16x16x32_bf16(af[ks], bf, acc[c], 0, 0, 0);
            }
        }
        #pragma unroll
        for (int c = 0; c < 2; ++c) {
            int col = (wave * 2 + c) * 16 + m16;
            float bv = b2[col];
            #pragma unroll
            for (int r = 0; r < 4; ++r) {
                int row = quad * 4 + r;
                Hsb[row][col] = f2bf(fmaxf(acc[c][r] + bv, 0.0f));
            }
        }
    }
    __syncthreads();

    // ---- phase 3: 16x64 = Hsb(16x128) @ Wp3(128x64) -> global Q2b (bf16, no bias)
    // wave computes column tile = wave
    {
        short8 hf[4];
        #pragma unroll
        for (int ks = 0; ks < 4; ++ks)
            hf[ks] = *(const short8*)(&Hsb[m16][ks * 32 + quad * 8]);
        floatx4 acc3 = (floatx4){0.f, 0.f, 0.f, 0.f};
        #pragma unroll
        for (int ks = 0; ks < 4; ++ks) {
            short8 bf = *(const short8*)(Wp3 + ((size_t)(wave * 4 + ks) * 64 + lane) * 8);
            acc3 = __builtin_amdgcn_mfma_f32_16x16x32_bf16(hf[ks], bf, acc3, 0, 0, 0);
        }
        int col = wave * 16 + m16;
        #pragma unroll
        for (int r = 0; r < 4; ++r) {
            long row = base + quad * 4 + r;
            Q2b[row * 64 + col] = f2bf(acc3[r]);
        }
    }
}

// ---------------------------------------------------------------- aggregation F=64 bf16 + bias + relu + Wl dot + pool-atomic
// 8 nodes/wave: 8 lanes x 8 feats (16B short8 gathers), single gather round.
// Per-node scalar goes straight into gsum[batch[node]] (512 addrs, ~13 atomics/us/addr - uncontended).
__global__ __launch_bounds__(256) void k_agg64_dot(const unsigned short* __restrict__ h,
                                                   const float* __restrict__ dis,
                                                   const int* __restrict__ row_ptr,
                                                   const int* __restrict__ csr_src,
                                                   const float* __restrict__ csr_norm,
                                                   const float* __restrict__ bias,
                                                   const float* __restrict__ Wl,
                                                   const int* __restrict__ batch,
                                                   float* __restrict__ gsum) {
    int gw = (blockIdx.x * 256 + threadIdx.x) >> 6;  // 12500 waves
    int lane = threadIdx.x & 63;
    int sub = lane >> 3, l8 = lane & 7;
    int node = gw * 8 + sub;                         // 100000 = 12500*8 exact
    int beg = row_ptr[node], end = row_ptr[node + 1];
    int idx[8]; float nn[8];
    #pragma unroll
    for (int u = 0; u < 8; ++u) {
        int ee = beg + u; int cl = ee < end ? ee : end - 1;
        idx[u] = csr_src[cl]; nn[u] = ee < end ? csr_norm[cl] : 0.0f;
    }
    float d = dis[node];
    short8 self = *(const short8*)(h + (size_t)node * 64 + l8 * 8);
    short8 g[8];
    #pragma unroll
    for (int u = 0; u < 8; ++u)
        g[u] = *(const short8*)(h + (size_t)idx[u] * 64 + l8 * 8);
    float a[8];
    init8(a, self, d * d);
    #pragma unroll
    for (int u = 0; u < 8; ++u) fma8(a, g[u], nn[u]);
    for (int e = beg + 8; e < end; e += 8) {         // rare remainder
        int idx2[8]; float nn2[8];
        #pragma unroll
        for (int u = 0; u < 8; ++u) {
            int ee = e + u; int cl = ee < end ? ee : end - 1;
            idx2[u] = csr_src[cl]; nn2[u] = ee < end ? csr_norm[cl] : 0.0f;
        }
        short8 g2[8];
        #pragma unroll
        for (int u = 0; u < 8; ++u)
            g2[u] = *(const short8*)(h + (size_t)idx2[u] * 64 + l8 * 8);
        #pragma unroll
        for (int u = 0; u < 8; ++u) fma8(a, g2[u], nn2[u]);
    }
    int f = l8 * 8;
    float v = 0.f;
    #pragma unroll
    for (int j = 0; j < 8; ++j)
        v = fmaf(fmaxf(a[j] + bias[f + j], 0.f), Wl[f + j], v);
    #pragma unroll
    for (int m = 4; m > 0; m >>= 1) v += __shfl_xor(v, m, 64);   // reduce within 8-lane group
    if (l8 == 0) atomicAdd(&gsum[batch[node]], v);
}

// ---------------------------------------------------------------- finalize: out[g] = gsum[g]/count[g] + bl
__global__ __launch_bounds__(256) void k_final(const float* __restrict__ gsum,
                                               const int* __restrict__ batch,
                                               const float* __restrict__ bl,
                                               float* __restrict__ out) {
    int g = blockIdx.x * 256 + threadIdx.x;
    if (g >= N_GRAPHS) return;
    int lo = 0, hi = N_NODES;
    while (lo < hi) { int m = (lo + hi) >> 1; if (batch[m] < g) lo = m + 1; else hi = m; }
    int lo2 = lo, hi2 = N_NODES;
    while (lo2 < hi2) { int m = (lo2 + hi2) >> 1; if (batch[m] < g + 1) lo2 = m + 1; else hi2 = m; }
    out[g] = gsum[g] / fmaxf((float)(lo2 - lo), 1.0f) + bl[0];
}

// ---------------------------------------------------------------- launcher
extern "C" void kernel_launch(void* const* d_in, const int* in_sizes, int n_in,
                              void* d_out, int out_size, void* d_ws, size_t ws_size,
                              hipStream_t stream) {
    const float* x     = (const float*)d_in[0];
    const int*   ei    = (const int*)d_in[1];     // [0..E) = src, [E..2E) = dst
    const int*   batch = (const int*)d_in[2];
    const float* W1 = (const float*)d_in[3];
    const float* b1 = (const float*)d_in[4];
    const float* W2 = (const float*)d_in[5];
    const float* b2 = (const float*)d_in[6];
    const float* W3 = (const float*)d_in[7];
    const float* b3 = (const float*)d_in[8];
    const float* Wl = (const float*)d_in[9];
    const float* bl = (const float*)d_in[10];
    float* out = (float*)d_out;

    const int* e_src = ei;
    const int* e_dst = ei + N_EDGES;

    char* ws = (char*)d_ws;
    size_t off = 0;
    auto alloc = [&](size_t bytes) -> char* {
        char* p = ws + off;
        off = (off + bytes + 255) & ~(size_t)255;
        return p;
    };
    int*   cnt      = (int*)  alloc((size_t)N_NODES * 4);
    float* gsum     = (float*)alloc((size_t)N_GRAPHS * 4);   // adjacent to cnt: one memset covers both
    float* dis      = (float*)alloc((size_t)N_NODES * 4);
    int*   row_ptr  = (int*)  alloc((size_t)(N_NODES + 1) * 4);
    int*   cursor   = (int*)  alloc((size_t)N_NODES * 4);
    int*   part     = (int*)  alloc(1024 * 4);
    int*   csr_src  = (int*)  alloc((size_t)N_EDGES * 4);
    float* csr_norm = (float*)alloc((size_t)N_EDGES * 4);
    unsigned short* P1b = (unsigned short*)alloc((size_t)N_NODES * 128 * 2); // h1 bf16
    unsigned short* Q2b = (unsigned short*)alloc((size_t)N_NODES * 64 * 2);  // h2@W3 bf16
    unsigned short* Wp2 = (unsigned short*)alloc((size_t)128 * 128 * 2);
    unsigned short* Wp3 = (unsigned short*)alloc((size_t)128 * 64 * 2);

    const int NB_N = (N_NODES + 255) / 256;   // 391
    const int NB_E = (N_EDGES + 255) / 256;

    // zero cnt + gsum in one fill (adjacent in carve-up)
    hipMemsetAsync(cnt, 0, (size_t)((char*)gsum - (char*)cnt) + (size_t)N_GRAPHS * 4, stream);
    k_hist<<<NB_E, 256, 0, stream>>>(e_dst, cnt);
    k_scan1<<<NB_N, 256, 0, stream>>>(cnt, part);
    k_scan3<<<NB_N, 256, 0, stream>>>(cnt, part, row_ptr, cursor, dis);
    k_scatter<<<NB_E, 256, 0, stream>>>(e_src, e_dst, dis, cursor, csr_src, csr_norm);

    // layer 1 fused: agg(F=3) + GEMM 3->128 + b1 + relu -> bf16 (+12 pack blocks)
    k_node1<<<NB1 + 12, 256, 0, stream>>>(x, dis, row_ptr, csr_src, csr_norm,
                                          W1, b1, P1b, W2, W3, Wp2, Wp3);

    // layers 2+3 fused (16-node blocks): agg(F=128) + GEMM2(+b2,relu) + GEMM3 -> Q2b bf16
    k_layer23<<<N_NODES / 16, 256, 0, stream>>>(P1b, dis, row_ptr, csr_src, csr_norm,
                                                Wp2, b2, Wp3, Q2b);

    // layer 3 aggregation + b3 + relu + dot(Wl) + pool atomic (8 nodes/wave)
    k_agg64_dot<<<N_NODES / 8 / 4, 256, 0, stream>>>(Q2b, dis, row_ptr, csr_src, csr_norm,
                                                     b3, Wl, batch, gsum);

    // finalize: mean + bl
    k_final<<<(N_GRAPHS + 255) / 256, 256, 0, stream>>>(gsum, batch, bl, out);
}

// Round 14
// 218.284 us; speedup vs baseline: 1.6439x; 1.6439x over previous
//
#include <hip/hip_runtime.h>

#define N_NODES 100000
#define N_EDGES 600000
#define N_GRAPHS 512

typedef __attribute__((ext_vector_type(8))) short short8;
typedef __attribute__((ext_vector_type(4))) float floatx4;

__device__ __forceinline__ unsigned short f2bf(float f) {   // RNE f32 -> bf16
    unsigned int u = __float_as_uint(f);
    u += 0x7FFFu + ((u >> 16) & 1u);
    return (unsigned short)(u >> 16);
}
__device__ __forceinline__ float bf_lo(unsigned int u) { return __uint_as_float(u << 16); }
__device__ __forceinline__ float bf_hi(unsigned int u) { return __uint_as_float(u & 0xFFFF0000u); }

__device__ __forceinline__ void fma8(float* a, short8 v, float n) {
    union { short8 s; unsigned int u[4]; } c; c.s = v;
    #pragma unroll
    for (int j = 0; j < 4; ++j) {
        a[2 * j]     = fmaf(bf_lo(c.u[j]), n, a[2 * j]);
        a[2 * j + 1] = fmaf(bf_hi(c.u[j]), n, a[2 * j + 1]);
    }
}
__device__ __forceinline__ void init8(float* a, short8 v, float s) {
    union { short8 s; unsigned int u[4]; } c; c.s = v;
    #pragma unroll
    for (int j = 0; j < 4; ++j) {
        a[2 * j]     = bf_lo(c.u[j]) * s;
        a[2 * j + 1] = bf_hi(c.u[j]) * s;
    }
}
__device__ __forceinline__ short8 pack8(const float* a) {
    short8 r;
    #pragma unroll
    for (int j = 0; j < 8; ++j) r[j] = (short)f2bf(a[j]);
    return r;
}

// ---------------------------------------------------------------- degree hist (cnt zeroed by memset)
__global__ void k_hist(const int* __restrict__ dst, int* cnt) {
    int e = blockIdx.x * 256 + threadIdx.x;
    if (e < N_EDGES) atomicAdd(&cnt[dst[e]], 1);
}

// ---------------------------------------------------------------- scan1: block sums of cnt
__global__ void k_scan1(const int* __restrict__ cnt, int* __restrict__ part) {
    __shared__ int s[256];
    int t = threadIdx.x;
    int i = blockIdx.x * 256 + t;
    int v = (i < N_NODES) ? cnt[i] : 0;
    s[t] = v; __syncthreads();
    for (int off = 128; off > 0; off >>= 1) {
        if (t < off) s[t] += s[t + off];
        __syncthreads();
    }
    if (t == 0) part[blockIdx.x] = s[0];
}

// ---------------------------------------------------------------- scan3: computes its own base from part[]
__global__ void k_scan3(const int* __restrict__ cnt, const int* __restrict__ part,
                        int* __restrict__ row_ptr, int* __restrict__ cursor,
                        float* __restrict__ dis) {
    __shared__ int s[256];
    __shared__ int pbaseS;
    int t = threadIdx.x;
    int psum = 0;
    for (int k = t; k < blockIdx.x; k += 256) psum += part[k];
    s[t] = psum; __syncthreads();
    for (int off = 128; off > 0; off >>= 1) {
        if (t < off) s[t] += s[t + off];
        __syncthreads();
    }
    if (t == 0) pbaseS = s[0];
    __syncthreads();
    int pbase = pbaseS;
    __syncthreads();
    int i = blockIdx.x * 256 + t;
    int v = (i < N_NODES) ? cnt[i] : 0;
    s[t] = v; __syncthreads();
    for (int off = 1; off < 256; off <<= 1) {
        int u = (t >= off) ? s[t - off] : 0;
        __syncthreads();
        s[t] += u;
        __syncthreads();
    }
    int ex = s[t] - v + pbase;
    if (i < N_NODES) {
        row_ptr[i] = ex; cursor[i] = ex;
        dis[i] = 1.0f / sqrtf((float)(v + 1));   // deg includes self-loop
    }
    if (blockIdx.x == 0 && t == 0) row_ptr[N_NODES] = N_EDGES;
}

// ---------------------------------------------------------------- CSR scatter
__global__ void k_scatter(const int* __restrict__ src, const int* __restrict__ dst,
                          const float* __restrict__ dis, int* __restrict__ cursor,
                          int* __restrict__ csr_src, float* __restrict__ csr_norm) {
    int e = blockIdx.x * 256 + threadIdx.x;
    if (e >= N_EDGES) return;
    int s = src[e], d = dst[e];
    int pos = atomicAdd(&cursor[d], 1);
    csr_src[pos] = s;
    csr_norm[pos] = dis[s] * dis[d];
}

// ---------------------------------------------------------------- pack W2/W3 to B-frag order (device fn)
__device__ __forceinline__ void pack_one(const float* __restrict__ W, unsigned short* __restrict__ out,
                                         int idx, int N) {
    int lane = idx & 63;
    int ks = (idx >> 6) & 3;
    int ct = idx >> 8;
    int n = ct * 16 + (lane & 15);
    int kbase = ks * 32 + (lane >> 4) * 8;
    #pragma unroll
    for (int j = 0; j < 8; ++j)
        out[(size_t)idx * 8 + j] = f2bf(W[(size_t)(kbase + j) * N + n]);
}

// ---------------------------------------------------------------- layer 1 fused: agg(F=3) + GEMM 3->128 + b1 + relu -> bf16
// 4 nodes/wave: 16 lanes per node. Last 12 blocks instead pack W2/W3 (fused dispatch).
#define NB1 6250
__global__ __launch_bounds__(256) void k_node1(const float* __restrict__ x,
                                               const float* __restrict__ dis,
                                               const int* __restrict__ row_ptr,
                                               const int* __restrict__ csr_src,
                                               const float* __restrict__ csr_norm,
                                               const float* __restrict__ W1,
                                               const float* __restrict__ b1,
                                               unsigned short* __restrict__ out,
                                               const float* __restrict__ W2,
                                               const float* __restrict__ W3,
                                               unsigned short* __restrict__ Wp2,
                                               unsigned short* __restrict__ Wp3) {
    int tid = threadIdx.x;
    if (blockIdx.x >= NB1) {                         // weight-pack role
        int idx = (blockIdx.x - NB1) * 256 + tid;    // 12 blocks = 3072
        if (idx < 2048) pack_one(W2, Wp2, idx, 128);
        else if (idx < 3072) pack_one(W3, Wp3, idx - 2048, 64);
        return;
    }
    __shared__ float Ws[384];
    __shared__ float bs[128];
    for (int i = tid; i < 384; i += 256) Ws[i] = W1[i];
    if (tid < 128) bs[tid] = b1[tid];
    __syncthreads();
    int gw = (blockIdx.x * 256 + tid) >> 6;          // 25000 waves
    int lane = tid & 63;
    int sub = lane >> 4, l16 = lane & 15;
    int node = gw * 4 + sub;                         // 100000 = 25000*4 exact
    int beg = row_ptr[node], end = row_ptr[node + 1];
    float p0 = 0.f, p1 = 0.f, p2 = 0.f;
    for (int e = beg + l16; e < end; e += 16) {
        int s = csr_src[e];
        float n = csr_norm[e];
        p0 = fmaf(x[s * 3 + 0], n, p0);
        p1 = fmaf(x[s * 3 + 1], n, p1);
        p2 = fmaf(x[s * 3 + 2], n, p2);
    }
    #pragma unroll
    for (int m = 8; m > 0; m >>= 1) {                // butterfly within 16-lane group
        p0 += __shfl_xor(p0, m, 64);
        p1 += __shfl_xor(p1, m, 64);
        p2 += __shfl_xor(p2, m, 64);
    }
    float d = dis[node], s2 = d * d;
    float a0 = fmaf(x[node * 3 + 0], s2, p0);
    float a1 = fmaf(x[node * 3 + 1], s2, p1);
    float a2 = fmaf(x[node * 3 + 2], s2, p2);
    int f = l16 * 8;
    float v[8];
    #pragma unroll
    for (int j = 0; j < 8; ++j)
        v[j] = fmaxf(bs[f + j] + a0 * Ws[f + j] + a1 * Ws[128 + f + j] + a2 * Ws[256 + f + j], 0.f);
    *(short8*)(out + (size_t)node * 128 + f) = pack8(v);
}

// ---------------------------------------------------------------- layers 2+3 fused, 16-node blocks:
// each wave aggregates 4 nodes in ONE gather round (16 lanes/node, 8 feats/lane) -> low VGPR, high occupancy.
// -> LDS -> MFMA GEMM2 (+b2, relu) -> LDS -> MFMA GEMM3 -> Q2b.  100000 = 6250 * 16 exact.
__global__ __launch_bounds__(256) void k_layer23(const unsigned short* __restrict__ h1,
                                                 const float* __restrict__ dis,
                                                 const int* __restrict__ row_ptr,
                                                 const int* __restrict__ csr_src,
                                                 const float* __restrict__ csr_norm,
                                                 const unsigned short* __restrict__ Wp2,
                                                 const float* __restrict__ b2,
                                                 const unsigned short* __restrict__ Wp3,
                                                 unsigned short* __restrict__ Q2b) {
    __shared__ unsigned short Asb[16][136];   // aggregated h1 tile
    __shared__ unsigned short Hsb[16][136];   // h2 tile
    int tid = threadIdx.x;
    int wave = tid >> 6, lane = tid & 63;
    int quad = lane >> 4, m16 = lane & 15;
    int base = blockIdx.x * 16;

    // ---- phase 1: 4 nodes per wave, all 8 gathers in flight, one latency round (common case)
    {
        int sub = lane >> 4, l16 = lane & 15;
        int r = wave * 4 + sub;
        int node = base + r;
        int beg = row_ptr[node], end = row_ptr[node + 1];
        int idx[8]; float nn[8];
        #pragma unroll
        for (int u = 0; u < 8; ++u) {
            int ee = beg + u; int cl = ee < end ? ee : end - 1;
            idx[u] = csr_src[cl]; nn[u] = ee < end ? csr_norm[cl] : 0.0f;
        }
        float d = dis[node];
        short8 self = *(const short8*)(h1 + (size_t)node * 128 + l16 * 8);
        short8 g[8];
        #pragma unroll
        for (int u = 0; u < 8; ++u)
            g[u] = *(const short8*)(h1 + (size_t)idx[u] * 128 + l16 * 8);
        float a[8];
        init8(a, self, d * d);
        #pragma unroll
        for (int u = 0; u < 8; ++u) fma8(a, g[u], nn[u]);
        for (int e = beg + 8; e < end; e += 8) {       // rare remainder (P(deg>8)~15%)
            int idx2[8]; float nn2[8];
            #pragma unroll
            for (int u = 0; u < 8; ++u) {
                int ee = e + u; int cl = ee < end ? ee : end - 1;
                idx2[u] = csr_src[cl]; nn2[u] = ee < end ? csr_norm[cl] : 0.0f;
            }
            short8 g2[8];
            #pragma unroll
            for (int u = 0; u < 8; ++u)
                g2[u] = *(const short8*)(h1 + (size_t)idx2[u] * 128 + l16 * 8);
            #pragma unroll
            for (int u = 0; u < 8; ++u) fma8(a, g2[u], nn2[u]);
        }
        *(short8*)(&Asb[r][l16 * 8]) = pack8(a);
    }
    __syncthreads();

    // ---- phase 2: 16x128 = Asb(16x128) @ Wp2(128x128), +b2, relu -> Hsb
    // wave computes column tiles {2*wave, 2*wave+1}
    {
        short8 af[4];
        #pragma unroll
        for (int ks = 0; ks < 4; ++ks)
            af[ks] = *(const short8*)(&Asb[m16][ks * 32 + quad * 8]);
        floatx4 acc[2];
        acc[0] = (floatx4){0.f, 0.f, 0.f, 0.f};
        acc[1] = (floatx4){0.f, 0.f, 0.f, 0.f};
        #pragma unroll
        for (int c = 0; c < 2; ++c) {
            int gct = wave * 2 + c;
            #pragma unroll
            for (int ks = 0; ks < 4; ++ks) {
                short8 bf = *(const short8*)(Wp2 + ((size_t)(gct * 4 + ks) * 64 + lane) * 8);
                acc[c] = __builtin_amdgcn_mfma_f32_16x16x32_bf16(af[ks], bf, acc[c], 0, 0, 0);
            }
        }
        #pragma unroll
        for (int c = 0; c < 2; ++c) {
            int col = (wave * 2 + c) * 16 + m16;
            float bv = b2[col];
            #pragma unroll
            for (int r = 0; r < 4; ++r) {
                int row = quad * 4 + r;
                Hsb[row][col] = f2bf(fmaxf(acc[c][r] + bv, 0.0f));
            }
        }
    }
    __syncthreads();

    // ---- phase 3: 16x64 = Hsb(16x128) @ Wp3(128x64) -> global Q2b (bf16, no bias)
    // wave computes column tile = wave
    {
        short8 hf[4];
        #pragma unroll
        for (int ks = 0; ks < 4; ++ks)
            hf[ks] = *(const short8*)(&Hsb[m16][ks * 32 + quad * 8]);
        floatx4 acc3 = (floatx4){0.f, 0.f, 0.f, 0.f};
        #pragma unroll
        for (int ks = 0; ks < 4; ++ks) {
            short8 bf = *(const short8*)(Wp3 + ((size_t)(wave * 4 + ks) * 64 + lane) * 8);
            acc3 = __builtin_amdgcn_mfma_f32_16x16x32_bf16(hf[ks], bf, acc3, 0, 0, 0);
        }
        int col = wave * 16 + m16;
        #pragma unroll
        for (int r = 0; r < 4; ++r) {
            long row = base + quad * 4 + r;
            Q2b[row * 64 + col] = f2bf(acc3[r]);
        }
    }
}

// ---------------------------------------------------------------- aggregation F=64 bf16 + bias + relu + Wl dot
// 8 nodes/wave: 8 lanes x 8 feats (16B short8 gathers), single gather round. No atomics.
__global__ __launch_bounds__(256) void k_agg64_dot(const unsigned short* __restrict__ h,
                                                   const float* __restrict__ dis,
                                                   const int* __restrict__ row_ptr,
                                                   const int* __restrict__ csr_src,
                                                   const float* __restrict__ csr_norm,
                                                   const float* __restrict__ bias,
                                                   const float* __restrict__ Wl,
                                                   float* __restrict__ s_out) {
    int gw = (blockIdx.x * 256 + threadIdx.x) >> 6;  // 12500 waves
    int lane = threadIdx.x & 63;
    int sub = lane >> 3, l8 = lane & 7;
    int node = gw * 8 + sub;                         // 100000 = 12500*8 exact
    int beg = row_ptr[node], end = row_ptr[node + 1];
    int idx[8]; float nn[8];
    #pragma unroll
    for (int u = 0; u < 8; ++u) {
        int ee = beg + u; int cl = ee < end ? ee : end - 1;
        idx[u] = csr_src[cl]; nn[u] = ee < end ? csr_norm[cl] : 0.0f;
    }
    float d = dis[node];
    short8 self = *(const short8*)(h + (size_t)node * 64 + l8 * 8);
    short8 g[8];
    #pragma unroll
    for (int u = 0; u < 8; ++u)
        g[u] = *(const short8*)(h + (size_t)idx[u] * 64 + l8 * 8);
    float a[8];
    init8(a, self, d * d);
    #pragma unroll
    for (int u = 0; u < 8; ++u) fma8(a, g[u], nn[u]);
    for (int e = beg + 8; e < end; e += 8) {         // rare remainder
        int idx2[8]; float nn2[8];
        #pragma unroll
        for (int u = 0; u < 8; ++u) {
            int ee = e + u; int cl = ee < end ? ee : end - 1;
            idx2[u] = csr_src[cl]; nn2[u] = ee < end ? csr_norm[cl] : 0.0f;
        }
        short8 g2[8];
        #pragma unroll
        for (int u = 0; u < 8; ++u)
            g2[u] = *(const short8*)(h + (size_t)idx2[u] * 64 + l8 * 8);
        #pragma unroll
        for (int u = 0; u < 8; ++u) fma8(a, g2[u], nn2[u]);
    }
    int f = l8 * 8;
    float v = 0.f;
    #pragma unroll
    for (int j = 0; j < 8; ++j)
        v = fmaf(fmaxf(a[j] + bias[f + j], 0.f), Wl[f + j], v);
    #pragma unroll
    for (int m = 4; m > 0; m >>= 1) v += __shfl_xor(v, m, 64);   // reduce within 8-lane group
    if (l8 == 0) s_out[node] = v;
}

// ---------------------------------------------------------------- pool over per-node scalars
__global__ __launch_bounds__(256) void k_pool2(const float* __restrict__ s,
                                               const int* __restrict__ batch,
                                               const float* __restrict__ bl,
                                               float* __restrict__ out) {
    int g = blockIdx.x;
    int tid = threadIdx.x;
    int lo = 0, hi = N_NODES;
    while (lo < hi) { int m = (lo + hi) >> 1; if (batch[m] < g) lo = m + 1; else hi = m; }
    int lo2 = lo, hi2 = N_NODES;
    while (lo2 < hi2) { int m = (lo2 + hi2) >> 1; if (batch[m] < g + 1) lo2 = m + 1; else hi2 = m; }
    float acc = 0.0f;
    for (int n = lo + tid; n < lo2; n += 256) acc += s[n];
    __shared__ float sm[256];
    sm[tid] = acc; __syncthreads();
    for (int off = 128; off > 0; off >>= 1) {
        if (tid < off) sm[tid] += sm[tid + off];
        __syncthreads();
    }
    if (tid == 0) out[g] = sm[0] / fmaxf((float)(lo2 - lo), 1.0f) + bl[0];
}

// ---------------------------------------------------------------- launcher
extern "C" void kernel_launch(void* const* d_in, const int* in_sizes, int n_in,
                              void* d_out, int out_size, void* d_ws, size_t ws_size,
                              hipStream_t stream) {
    const float* x     = (const float*)d_in[0];
    const int*   ei    = (const int*)d_in[1];     // [0..E) = src, [E..2E) = dst
    const int*   batch = (const int*)d_in[2];
    const float* W1 = (const float*)d_in[3];
    const float* b1 = (const float*)d_in[4];
    const float* W2 = (const float*)d_in[5];
    const float* b2 = (const float*)d_in[6];
    const float* W3 = (const float*)d_in[7];
    const float* b3 = (const float*)d_in[8];
    const float* Wl = (const float*)d_in[9];
    const float* bl = (const float*)d_in[10];
    float* out = (float*)d_out;

    const int* e_src = ei;
    const int* e_dst = ei + N_EDGES;

    char* ws = (char*)d_ws;
    size_t off = 0;
    auto alloc = [&](size_t bytes) -> char* {
        char* p = ws + off;
        off = (off + bytes + 255) & ~(size_t)255;
        return p;
    };
    int*   cnt      = (int*)  alloc((size_t)N_NODES * 4);
    float* dis      = (float*)alloc((size_t)N_NODES * 4);
    int*   row_ptr  = (int*)  alloc((size_t)(N_NODES + 1) * 4);
    int*   cursor   = (int*)  alloc((size_t)N_NODES * 4);
    int*   part     = (int*)  alloc(1024 * 4);
    int*   csr_src  = (int*)  alloc((size_t)N_EDGES * 4);
    float* csr_norm = (float*)alloc((size_t)N_EDGES * 4);
    float* nscal    = (float*)alloc((size_t)N_NODES * 4);
    unsigned short* P1b = (unsigned short*)alloc((size_t)N_NODES * 128 * 2); // h1 bf16
    unsigned short* Q2b = (unsigned short*)alloc((size_t)N_NODES * 64 * 2);  // h2@W3 bf16
    unsigned short* Wp2 = (unsigned short*)alloc((size_t)128 * 128 * 2);
    unsigned short* Wp3 = (unsigned short*)alloc((size_t)128 * 64 * 2);

    const int NB_N = (N_NODES + 255) / 256;   // 391
    const int NB_E = (N_EDGES + 255) / 256;

    hipMemsetAsync(cnt, 0, (size_t)N_NODES * 4, stream);
    k_hist<<<NB_E, 256, 0, stream>>>(e_dst, cnt);
    k_scan1<<<NB_N, 256, 0, stream>>>(cnt, part);
    k_scan3<<<NB_N, 256, 0, stream>>>(cnt, part, row_ptr, cursor, dis);
    k_scatter<<<NB_E, 256, 0, stream>>>(e_src, e_dst, dis, cursor, csr_src, csr_norm);

    // layer 1 fused: agg(F=3) + GEMM 3->128 + b1 + relu -> bf16 (+12 pack blocks)
    k_node1<<<NB1 + 12, 256, 0, stream>>>(x, dis, row_ptr, csr_src, csr_norm,
                                          W1, b1, P1b, W2, W3, Wp2, Wp3);

    // layers 2+3 fused (16-node blocks): agg(F=128) + GEMM2(+b2,relu) + GEMM3 -> Q2b bf16
    k_layer23<<<N_NODES / 16, 256, 0, stream>>>(P1b, dis, row_ptr, csr_src, csr_norm,
                                                Wp2, b2, Wp3, Q2b);

    // layer 3 aggregation + b3 + relu + dot(Wl)  (8 nodes/wave, no atomics)
    k_agg64_dot<<<N_NODES / 8 / 4, 256, 0, stream>>>(Q2b, dis, row_ptr, csr_src, csr_norm,
                                                     b3, Wl, nscal);

    // mean pool (+ bl) over per-node scalars
    k_pool2<<<N_GRAPHS, 256, 0, stream>>>(nscal, batch, bl, out);
}

// Round 15
// 208.996 us; speedup vs baseline: 1.7170x; 1.0444x over previous
//
#include <hip/hip_runtime.h>

#define N_NODES 100000
#define N_EDGES 600000
#define N_GRAPHS 512

typedef __attribute__((ext_vector_type(8))) short short8;
typedef __attribute__((ext_vector_type(4))) float floatx4;
typedef __attribute__((ext_vector_type(2))) float floatx2;

__device__ __forceinline__ unsigned short f2bf(float f) {   // RNE f32 -> bf16
    unsigned int u = __float_as_uint(f);
    u += 0x7FFFu + ((u >> 16) & 1u);
    return (unsigned short)(u >> 16);
}
__device__ __forceinline__ short8 pack8(const float* a) {
    short8 r;
    #pragma unroll
    for (int j = 0; j < 8; ++j) r[j] = (short)f2bf(a[j]);
    return r;
}

// ---- fp8 e4m3 (OCP, gfx950 HW cvt) helpers: 8 feats <-> uint2 (8 bytes) ----
__device__ __forceinline__ uint2 pack_fp8x8(const float* v) {
    uint2 r;
    unsigned int a = 0;
    a = __builtin_amdgcn_cvt_pk_fp8_f32(v[0], v[1], a, 0);
    a = __builtin_amdgcn_cvt_pk_fp8_f32(v[2], v[3], a, 1);
    unsigned int b = 0;
    b = __builtin_amdgcn_cvt_pk_fp8_f32(v[4], v[5], b, 0);
    b = __builtin_amdgcn_cvt_pk_fp8_f32(v[6], v[7], b, 1);
    r.x = a; r.y = b;
    return r;
}
__device__ __forceinline__ unsigned char f2fp8(float v) {
    return (unsigned char)(__builtin_amdgcn_cvt_pk_fp8_f32(v, v, 0u, 0) & 0xFFu);
}
__device__ __forceinline__ void fma8_fp8(float* a, uint2 v, float n) {
    floatx2 p;
    p = __builtin_amdgcn_cvt_pk_f32_fp8(v.x, 0); a[0] = fmaf(p[0], n, a[0]); a[1] = fmaf(p[1], n, a[1]);
    p = __builtin_amdgcn_cvt_pk_f32_fp8(v.x, 1); a[2] = fmaf(p[0], n, a[2]); a[3] = fmaf(p[1], n, a[3]);
    p = __builtin_amdgcn_cvt_pk_f32_fp8(v.y, 0); a[4] = fmaf(p[0], n, a[4]); a[5] = fmaf(p[1], n, a[5]);
    p = __builtin_amdgcn_cvt_pk_f32_fp8(v.y, 1); a[6] = fmaf(p[0], n, a[6]); a[7] = fmaf(p[1], n, a[7]);
}
__device__ __forceinline__ void init8_fp8(float* a, uint2 v, float s) {
    floatx2 p;
    p = __builtin_amdgcn_cvt_pk_f32_fp8(v.x, 0); a[0] = p[0] * s; a[1] = p[1] * s;
    p = __builtin_amdgcn_cvt_pk_f32_fp8(v.x, 1); a[2] = p[0] * s; a[3] = p[1] * s;
    p = __builtin_amdgcn_cvt_pk_f32_fp8(v.y, 0); a[4] = p[0] * s; a[5] = p[1] * s;
    p = __builtin_amdgcn_cvt_pk_f32_fp8(v.y, 1); a[6] = p[0] * s; a[7] = p[1] * s;
}

// ---------------------------------------------------------------- degree hist (cnt zeroed by memset)
__global__ void k_hist(const int* __restrict__ dst, int* cnt) {
    int e = blockIdx.x * 256 + threadIdx.x;
    if (e < N_EDGES) atomicAdd(&cnt[dst[e]], 1);
}

// ---------------------------------------------------------------- scan1: block sums of cnt
__global__ void k_scan1(const int* __restrict__ cnt, int* __restrict__ part) {
    __shared__ int s[256];
    int t = threadIdx.x;
    int i = blockIdx.x * 256 + t;
    int v = (i < N_NODES) ? cnt[i] : 0;
    s[t] = v; __syncthreads();
    for (int off = 128; off > 0; off >>= 1) {
        if (t < off) s[t] += s[t + off];
        __syncthreads();
    }
    if (t == 0) part[blockIdx.x] = s[0];
}

// ---------------------------------------------------------------- scan3: computes its own base from part[]
__global__ void k_scan3(const int* __restrict__ cnt, const int* __restrict__ part,
                        int* __restrict__ row_ptr, int* __restrict__ cursor,
                        float* __restrict__ dis) {
    __shared__ int s[256];
    __shared__ int pbaseS;
    int t = threadIdx.x;
    int psum = 0;
    for (int k = t; k < blockIdx.x; k += 256) psum += part[k];
    s[t] = psum; __syncthreads();
    for (int off = 128; off > 0; off >>= 1) {
        if (t < off) s[t] += s[t + off];
        __syncthreads();
    }
    if (t == 0) pbaseS = s[0];
    __syncthreads();
    int pbase = pbaseS;
    __syncthreads();
    int i = blockIdx.x * 256 + t;
    int v = (i < N_NODES) ? cnt[i] : 0;
    s[t] = v; __syncthreads();
    for (int off = 1; off < 256; off <<= 1) {
        int u = (t >= off) ? s[t - off] : 0;
        __syncthreads();
        s[t] += u;
        __syncthreads();
    }
    int ex = s[t] - v + pbase;
    if (i < N_NODES) {
        row_ptr[i] = ex; cursor[i] = ex;
        dis[i] = 1.0f / sqrtf((float)(v + 1));   // deg includes self-loop
    }
    if (blockIdx.x == 0 && t == 0) row_ptr[N_NODES] = N_EDGES;
}

// ---------------------------------------------------------------- CSR scatter
__global__ void k_scatter(const int* __restrict__ src, const int* __restrict__ dst,
                          const float* __restrict__ dis, int* __restrict__ cursor,
                          int* __restrict__ csr_src, float* __restrict__ csr_norm) {
    int e = blockIdx.x * 256 + threadIdx.x;
    if (e >= N_EDGES) return;
    int s = src[e], d = dst[e];
    int pos = atomicAdd(&cursor[d], 1);
    csr_src[pos] = s;
    csr_norm[pos] = dis[s] * dis[d];
}

// ---------------------------------------------------------------- pack W2/W3 to B-frag order (device fn)
__device__ __forceinline__ void pack_one(const float* __restrict__ W, unsigned short* __restrict__ out,
                                         int idx, int N) {
    int lane = idx & 63;
    int ks = (idx >> 6) & 3;
    int ct = idx >> 8;
    int n = ct * 16 + (lane & 15);
    int kbase = ks * 32 + (lane >> 4) * 8;
    #pragma unroll
    for (int j = 0; j < 8; ++j)
        out[(size_t)idx * 8 + j] = f2bf(W[(size_t)(kbase + j) * N + n]);
}

// ---------------------------------------------------------------- layer 1 fused: agg(F=3) + GEMM 3->128 + b1 + relu -> fp8
// 4 nodes/wave: 16 lanes per node. Last 12 blocks instead pack W2/W3 (fused dispatch).
#define NB1 6250
__global__ __launch_bounds__(256) void k_node1(const float* __restrict__ x,
                                               const float* __restrict__ dis,
                                               const int* __restrict__ row_ptr,
                                               const int* __restrict__ csr_src,
                                               const float* __restrict__ csr_norm,
                                               const float* __restrict__ W1,
                                               const float* __restrict__ b1,
                                               unsigned char* __restrict__ out,
                                               const float* __restrict__ W2,
                                               const float* __restrict__ W3,
                                               unsigned short* __restrict__ Wp2,
                                               unsigned short* __restrict__ Wp3) {
    int tid = threadIdx.x;
    if (blockIdx.x >= NB1) {                         // weight-pack role
        int idx = (blockIdx.x - NB1) * 256 + tid;    // 12 blocks = 3072
        if (idx < 2048) pack_one(W2, Wp2, idx, 128);
        else if (idx < 3072) pack_one(W3, Wp3, idx - 2048, 64);
        return;
    }
    __shared__ float Ws[384];
    __shared__ float bs[128];
    for (int i = tid; i < 384; i += 256) Ws[i] = W1[i];
    if (tid < 128) bs[tid] = b1[tid];
    __syncthreads();
    int gw = (blockIdx.x * 256 + tid) >> 6;          // 25000 waves
    int lane = tid & 63;
    int sub = lane >> 4, l16 = lane & 15;
    int node = gw * 4 + sub;                         // 100000 = 25000*4 exact
    int beg = row_ptr[node], end = row_ptr[node + 1];
    float p0 = 0.f, p1 = 0.f, p2 = 0.f;
    for (int e = beg + l16; e < end; e += 16) {
        int s = csr_src[e];
        float n = csr_norm[e];
        p0 = fmaf(x[s * 3 + 0], n, p0);
        p1 = fmaf(x[s * 3 + 1], n, p1);
        p2 = fmaf(x[s * 3 + 2], n, p2);
    }
    #pragma unroll
    for (int m = 8; m > 0; m >>= 1) {                // butterfly within 16-lane group
        p0 += __shfl_xor(p0, m, 64);
        p1 += __shfl_xor(p1, m, 64);
        p2 += __shfl_xor(p2, m, 64);
    }
    float d = dis[node], s2 = d * d;
    float a0 = fmaf(x[node * 3 + 0], s2, p0);
    float a1 = fmaf(x[node * 3 + 1], s2, p1);
    float a2 = fmaf(x[node * 3 + 2], s2, p2);
    int f = l16 * 8;
    float v[8];
    #pragma unroll
    for (int j = 0; j < 8; ++j)
        v[j] = fmaxf(bs[f + j] + a0 * Ws[f + j] + a1 * Ws[128 + f + j] + a2 * Ws[256 + f + j], 0.f);
    *(uint2*)(out + (size_t)node * 128 + f) = pack_fp8x8(v);
}

// ---------------------------------------------------------------- layers 2+3 fused, 16-node blocks:
// agg(F=128 fp8: rows are 128B = 2 lines): 16 lanes/node, 8B uint2 gathers, 8 in flight.
// -> bf16 LDS -> MFMA GEMM2 (+b2, relu) -> LDS -> MFMA GEMM3 -> Q2 fp8.  100000 = 6250*16.
__global__ __launch_bounds__(256) void k_layer23(const unsigned char* __restrict__ h1,
                                                 const float* __restrict__ dis,
                                                 const int* __restrict__ row_ptr,
                                                 const int* __restrict__ csr_src,
                                                 const float* __restrict__ csr_norm,
                                                 const unsigned short* __restrict__ Wp2,
                                                 const float* __restrict__ b2,
                                                 const unsigned short* __restrict__ Wp3,
                                                 unsigned char* __restrict__ Q2f8) {
    __shared__ unsigned short Asb[16][136];   // aggregated h1 tile (bf16 for MFMA)
    __shared__ unsigned short Hsb[16][136];   // h2 tile
    int tid = threadIdx.x;
    int wave = tid >> 6, lane = tid & 63;
    int quad = lane >> 4, m16 = lane & 15;
    int base = blockIdx.x * 16;

    // ---- phase 1: 4 nodes per wave, all 8 gathers in flight, one latency round (common case)
    {
        int sub = lane >> 4, l16 = lane & 15;
        int r = wave * 4 + sub;
        int node = base + r;
        int beg = row_ptr[node], end = row_ptr[node + 1];
        int idx[8]; float nn[8];
        #pragma unroll
        for (int u = 0; u < 8; ++u) {
            int ee = beg + u; int cl = ee < end ? ee : end - 1;
            idx[u] = csr_src[cl]; nn[u] = ee < end ? csr_norm[cl] : 0.0f;
        }
        float d = dis[node];
        uint2 self = *(const uint2*)(h1 + (size_t)node * 128 + l16 * 8);
        uint2 g[8];
        #pragma unroll
        for (int u = 0; u < 8; ++u)
            g[u] = *(const uint2*)(h1 + (size_t)idx[u] * 128 + l16 * 8);
        float a[8];
        init8_fp8(a, self, d * d);
        #pragma unroll
        for (int u = 0; u < 8; ++u) fma8_fp8(a, g[u], nn[u]);
        for (int e = beg + 8; e < end; e += 8) {       // rare remainder (P(deg>8)~15%)
            int idx2[8]; float nn2[8];
            #pragma unroll
            for (int u = 0; u < 8; ++u) {
                int ee = e + u; int cl = ee < end ? ee : end - 1;
                idx2[u] = csr_src[cl]; nn2[u] = ee < end ? csr_norm[cl] : 0.0f;
            }
            uint2 g2[8];
            #pragma unroll
            for (int u = 0; u < 8; ++u)
                g2[u] = *(const uint2*)(h1 + (size_t)idx2[u] * 128 + l16 * 8);
            #pragma unroll
            for (int u = 0; u < 8; ++u) fma8_fp8(a, g2[u], nn2[u]);
        }
        *(short8*)(&Asb[r][l16 * 8]) = pack8(a);      // bf16 into LDS for MFMA
    }
    __syncthreads();

    // ---- phase 2: 16x128 = Asb(16x128) @ Wp2(128x128), +b2, relu -> Hsb
    // wave computes column tiles {2*wave, 2*wave+1}
    {
        short8 af[4];
        #pragma unroll
        for (int ks = 0; ks < 4; ++ks)
            af[ks] = *(const short8*)(&Asb[m16][ks * 32 + quad * 8]);
        floatx4 acc[2];
        acc[0] = (floatx4){0.f, 0.f, 0.f, 0.f};
        acc[1] = (floatx4){0.f, 0.f, 0.f, 0.f};
        #pragma unroll
        for (int c = 0; c < 2; ++c) {
            int gct = wave * 2 + c;
            #pragma unroll
            for (int ks = 0; ks < 4; ++ks) {
                short8 bf = *(const short8*)(Wp2 + ((size_t)(gct * 4 + ks) * 64 + lane) * 8);
                acc[c] = __builtin_amdgcn_mfma_f32_16x16x32_bf16(af[ks], bf, acc[c], 0, 0, 0);
            }
        }
        #pragma unroll
        for (int c = 0; c < 2; ++c) {
            int col = (wave * 2 + c) * 16 + m16;
            float bv = b2[col];
            #pragma unroll
            for (int r = 0; r < 4; ++r) {
                int row = quad * 4 + r;
                Hsb[row][col] = f2bf(fmaxf(acc[c][r] + bv, 0.0f));
            }
        }
    }
    __syncthreads();

    // ---- phase 3: 16x64 = Hsb(16x128) @ Wp3(128x64) -> global Q2 (fp8, no bias)
    // wave computes column tile = wave
    {
        short8 hf[4];
        #pragma unroll
        for (int ks = 0; ks < 4; ++ks)
            hf[ks] = *(const short8*)(&Hsb[m16][ks * 32 + quad * 8]);
        floatx4 acc3 = (floatx4){0.f, 0.f, 0.f, 0.f};
        #pragma unroll
        for (int ks = 0; ks < 4; ++ks) {
            short8 bf = *(const short8*)(Wp3 + ((size_t)(wave * 4 + ks) * 64 + lane) * 8);
            acc3 = __builtin_amdgcn_mfma_f32_16x16x32_bf16(hf[ks], bf, acc3, 0, 0, 0);
        }
        int col = wave * 16 + m16;
        #pragma unroll
        for (int r = 0; r < 4; ++r) {
            long row = base + quad * 4 + r;
            Q2f8[row * 64 + col] = f2fp8(acc3[r]);
        }
    }
}

// ---------------------------------------------------------------- aggregation F=64 fp8 (row = 64B = ONE line)
// + bias + relu + Wl dot. 8 nodes/wave: 8 lanes x 8 feats (8B uint2 gathers), single gather round.
__global__ __launch_bounds__(256) void k_agg64_dot(const unsigned char* __restrict__ h,
                                                   const float* __restrict__ dis,
                                                   const int* __restrict__ row_ptr,
                                                   const int* __restrict__ csr_src,
                                                   const float* __restrict__ csr_norm,
                                                   const float* __restrict__ bias,
                                                   const float* __restrict__ Wl,
                                                   float* __restrict__ s_out) {
    int gw = (blockIdx.x * 256 + threadIdx.x) >> 6;  // 12500 waves
    int lane = threadIdx.x & 63;
    int sub = lane >> 3, l8 = lane & 7;
    int node = gw * 8 + sub;                         // 100000 = 12500*8 exact
    int beg = row_ptr[node], end = row_ptr[node + 1];
    int idx[8]; float nn[8];
    #pragma unroll
    for (int u = 0; u < 8; ++u) {
        int ee = beg + u; int cl = ee < end ? ee : end - 1;
        idx[u] = csr_src[cl]; nn[u] = ee < end ? csr_norm[cl] : 0.0f;
    }
    float d = dis[node];
    uint2 self = *(const uint2*)(h + (size_t)node * 64 + l8 * 8);
    uint2 g[8];
    #pragma unroll
    for (int u = 0; u < 8; ++u)
        g[u] = *(const uint2*)(h + (size_t)idx[u] * 64 + l8 * 8);
    float a[8];
    init8_fp8(a, self, d * d);
    #pragma unroll
    for (int u = 0; u < 8; ++u) fma8_fp8(a, g[u], nn[u]);
    for (int e = beg + 8; e < end; e += 8) {         // rare remainder
        int idx2[8]; float nn2[8];
        #pragma unroll
        for (int u = 0; u < 8; ++u) {
            int ee = e + u; int cl = ee < end ? ee : end - 1;
            idx2[u] = csr_src[cl]; nn2[u] = ee < end ? csr_norm[cl] : 0.0f;
        }
        uint2 g2[8];
        #pragma unroll
        for (int u = 0; u < 8; ++u)
            g2[u] = *(const uint2*)(h + (size_t)idx2[u] * 64 + l8 * 8);
        #pragma unroll
        for (int u = 0; u < 8; ++u) fma8_fp8(a, g2[u], nn2[u]);
    }
    int f = l8 * 8;
    float v = 0.f;
    #pragma unroll
    for (int j = 0; j < 8; ++j)
        v = fmaf(fmaxf(a[j] + bias[f + j], 0.f), Wl[f + j], v);
    #pragma unroll
    for (int m = 4; m > 0; m >>= 1) v += __shfl_xor(v, m, 64);   // reduce within 8-lane group
    if (l8 == 0) s_out[node] = v;
}

// ---------------------------------------------------------------- pool over per-node scalars
__global__ __launch_bounds__(256) void k_pool2(const float* __restrict__ s,
                                               const int* __restrict__ batch,
                                               const float* __restrict__ bl,
                                               float* __restrict__ out) {
    int g = blockIdx.x;
    int tid = threadIdx.x;
    int lo = 0, hi = N_NODES;
    while (lo < hi) { int m = (lo + hi) >> 1; if (batch[m] < g) lo = m + 1; else hi = m; }
    int lo2 = lo, hi2 = N_NODES;
    while (lo2 < hi2) { int m = (lo2 + hi2) >> 1; if (batch[m] < g + 1) lo2 = m + 1; else hi2 = m; }
    float acc = 0.0f;
    for (int n = lo + tid; n < lo2; n += 256) acc += s[n];
    __shared__ float sm[256];
    sm[tid] = acc; __syncthreads();
    for (int off = 128; off > 0; off >>= 1) {
        if (tid < off) sm[tid] += sm[tid + off];
        __syncthreads();
    }
    if (tid == 0) out[g] = sm[0] / fmaxf((float)(lo2 - lo), 1.0f) + bl[0];
}

// ---------------------------------------------------------------- launcher
extern "C" void kernel_launch(void* const* d_in, const int* in_sizes, int n_in,
                              void* d_out, int out_size, void* d_ws, size_t ws_size,
                              hipStream_t stream) {
    const float* x     = (const float*)d_in[0];
    const int*   ei    = (const int*)d_in[1];     // [0..E) = src, [E..2E) = dst
    const int*   batch = (const int*)d_in[2];
    const float* W1 = (const float*)d_in[3];
    const float* b1 = (const float*)d_in[4];
    const float* W2 = (const float*)d_in[5];
    const float* b2 = (const float*)d_in[6];
    const float* W3 = (const float*)d_in[7];
    const float* b3 = (const float*)d_in[8];
    const float* Wl = (const float*)d_in[9];
    const float* bl = (const float*)d_in[10];
    float* out = (float*)d_out;

    const int* e_src = ei;
    const int* e_dst = ei + N_EDGES;

    char* ws = (char*)d_ws;
    size_t off = 0;
    auto alloc = [&](size_t bytes) -> char* {
        char* p = ws + off;
        off = (off + bytes + 255) & ~(size_t)255;
        return p;
    };
    int*   cnt      = (int*)  alloc((size_t)N_NODES * 4);
    float* dis      = (float*)alloc((size_t)N_NODES * 4);
    int*   row_ptr  = (int*)  alloc((size_t)(N_NODES + 1) * 4);
    int*   cursor   = (int*)  alloc((size_t)N_NODES * 4);
    int*   part     = (int*)  alloc(1024 * 4);
    int*   csr_src  = (int*)  alloc((size_t)N_EDGES * 4);
    float* csr_norm = (float*)alloc((size_t)N_EDGES * 4);
    float* nscal    = (float*)alloc((size_t)N_NODES * 4);
    unsigned char*  P1f8 = (unsigned char*) alloc((size_t)N_NODES * 128);    // h1 fp8 (128B/row, 2 lines)
    unsigned char*  Q2f8 = (unsigned char*) alloc((size_t)N_NODES * 64);     // h2@W3 fp8 (64B/row, 1 line)
    unsigned short* Wp2  = (unsigned short*)alloc((size_t)128 * 128 * 2);
    unsigned short* Wp3  = (unsigned short*)alloc((size_t)128 * 64 * 2);

    const int NB_N = (N_NODES + 255) / 256;   // 391
    const int NB_E = (N_EDGES + 255) / 256;

    hipMemsetAsync(cnt, 0, (size_t)N_NODES * 4, stream);
    k_hist<<<NB_E, 256, 0, stream>>>(e_dst, cnt);
    k_scan1<<<NB_N, 256, 0, stream>>>(cnt, part);
    k_scan3<<<NB_N, 256, 0, stream>>>(cnt, part, row_ptr, cursor, dis);
    k_scatter<<<NB_E, 256, 0, stream>>>(e_src, e_dst, dis, cursor, csr_src, csr_norm);

    // layer 1 fused: agg(F=3) + GEMM 3->128 + b1 + relu -> fp8 (+12 pack blocks)
    k_node1<<<NB1 + 12, 256, 0, stream>>>(x, dis, row_ptr, csr_src, csr_norm,
                                          W1, b1, P1f8, W2, W3, Wp2, Wp3);

    // layers 2+3 fused (16-node blocks): agg(F=128 fp8) + GEMM2(+b2,relu) + GEMM3 -> Q2 fp8
    k_layer23<<<N_NODES / 16, 256, 0, stream>>>(P1f8, dis, row_ptr, csr_src, csr_norm,
                                                Wp2, b2, Wp3, Q2f8);

    // layer 3 aggregation (fp8 rows = 1 line) + b3 + relu + dot(Wl)
    k_agg64_dot<<<N_NODES / 8 / 4, 256, 0, stream>>>(Q2f8, dis, row_ptr, csr_src, csr_norm,
                                                     b3, Wl, nscal);

    // mean pool (+ bl) over per-node scalars
    k_pool2<<<N_GRAPHS, 256, 0, stream>>>(nscal, batch, bl, out);
}

// Round 16
// 203.797 us; speedup vs baseline: 1.7608x; 1.0255x over previous
//
#include <hip/hip_runtime.h>

#define N_NODES 100000
#define N_EDGES 600000
#define N_GRAPHS 512

typedef __attribute__((ext_vector_type(8))) short short8;
typedef __attribute__((ext_vector_type(4))) float floatx4;
typedef __attribute__((ext_vector_type(2))) float floatx2;

__device__ __forceinline__ unsigned short f2bf(float f) {   // RNE f32 -> bf16
    unsigned int u = __float_as_uint(f);
    u += 0x7FFFu + ((u >> 16) & 1u);
    return (unsigned short)(u >> 16);
}
__device__ __forceinline__ short8 pack8(const float* a) {
    short8 r;
    #pragma unroll
    for (int j = 0; j < 8; ++j) r[j] = (short)f2bf(a[j]);
    return r;
}

// ---- fp8 e4m3 (OCP, gfx950 HW cvt) helpers ----
__device__ __forceinline__ uint2 pack_fp8x8(const float* v) {
    uint2 r;
    unsigned int a = 0;
    a = __builtin_amdgcn_cvt_pk_fp8_f32(v[0], v[1], a, 0);
    a = __builtin_amdgcn_cvt_pk_fp8_f32(v[2], v[3], a, 1);
    unsigned int b = 0;
    b = __builtin_amdgcn_cvt_pk_fp8_f32(v[4], v[5], b, 0);
    b = __builtin_amdgcn_cvt_pk_fp8_f32(v[6], v[7], b, 1);
    r.x = a; r.y = b;
    return r;
}
__device__ __forceinline__ unsigned char f2fp8(float v) {
    return (unsigned char)(__builtin_amdgcn_cvt_pk_fp8_f32(v, v, 0u, 0) & 0xFFu);
}
__device__ __forceinline__ void fma4_fp8(float* a, unsigned int w, float n) {
    floatx2 p;
    p = __builtin_amdgcn_cvt_pk_f32_fp8(w, 0); a[0] = fmaf(p[0], n, a[0]); a[1] = fmaf(p[1], n, a[1]);
    p = __builtin_amdgcn_cvt_pk_f32_fp8(w, 1); a[2] = fmaf(p[0], n, a[2]); a[3] = fmaf(p[1], n, a[3]);
}
__device__ __forceinline__ void init4_fp8(float* a, unsigned int w, float s) {
    floatx2 p;
    p = __builtin_amdgcn_cvt_pk_f32_fp8(w, 0); a[0] = p[0] * s; a[1] = p[1] * s;
    p = __builtin_amdgcn_cvt_pk_f32_fp8(w, 1); a[2] = p[0] * s; a[3] = p[1] * s;
}
__device__ __forceinline__ void fma16_fp8(float* a, uint4 v, float n) {
    fma4_fp8(a +  0, v.x, n); fma4_fp8(a +  4, v.y, n);
    fma4_fp8(a +  8, v.z, n); fma4_fp8(a + 12, v.w, n);
}
__device__ __forceinline__ void init16_fp8(float* a, uint4 v, float s) {
    init4_fp8(a +  0, v.x, s); init4_fp8(a +  4, v.y, s);
    init4_fp8(a +  8, v.z, s); init4_fp8(a + 12, v.w, s);
}

// ---------------------------------------------------------------- degree hist (cnt zeroed by memset)
__global__ void k_hist(const int* __restrict__ dst, int* cnt) {
    int e = blockIdx.x * 256 + threadIdx.x;
    if (e < N_EDGES) atomicAdd(&cnt[dst[e]], 1);
}

// ---------------------------------------------------------------- scan1: block sums of cnt
__global__ void k_scan1(const int* __restrict__ cnt, int* __restrict__ part) {
    __shared__ int s[256];
    int t = threadIdx.x;
    int i = blockIdx.x * 256 + t;
    int v = (i < N_NODES) ? cnt[i] : 0;
    s[t] = v; __syncthreads();
    for (int off = 128; off > 0; off >>= 1) {
        if (t < off) s[t] += s[t + off];
        __syncthreads();
    }
    if (t == 0) part[blockIdx.x] = s[0];
}

// ---------------------------------------------------------------- scan3: computes its own base from part[]
__global__ void k_scan3(const int* __restrict__ cnt, const int* __restrict__ part,
                        int* __restrict__ row_ptr, int* __restrict__ cursor,
                        float* __restrict__ dis) {
    __shared__ int s[256];
    __shared__ int pbaseS;
    int t = threadIdx.x;
    int psum = 0;
    for (int k = t; k < blockIdx.x; k += 256) psum += part[k];
    s[t] = psum; __syncthreads();
    for (int off = 128; off > 0; off >>= 1) {
        if (t < off) s[t] += s[t + off];
        __syncthreads();
    }
    if (t == 0) pbaseS = s[0];
    __syncthreads();
    int pbase = pbaseS;
    __syncthreads();
    int i = blockIdx.x * 256 + t;
    int v = (i < N_NODES) ? cnt[i] : 0;
    s[t] = v; __syncthreads();
    for (int off = 1; off < 256; off <<= 1) {
        int u = (t >= off) ? s[t - off] : 0;
        __syncthreads();
        s[t] += u;
        __syncthreads();
    }
    int ex = s[t] - v + pbase;
    if (i < N_NODES) {
        row_ptr[i] = ex; cursor[i] = ex;
        dis[i] = 1.0f / sqrtf((float)(v + 1));   // deg includes self-loop
    }
    if (blockIdx.x == 0 && t == 0) row_ptr[N_NODES] = N_EDGES;
}

// ---------------------------------------------------------------- CSR scatter
__global__ void k_scatter(const int* __restrict__ src, const int* __restrict__ dst,
                          const float* __restrict__ dis, int* __restrict__ cursor,
                          int* __restrict__ csr_src, float* __restrict__ csr_norm) {
    int e = blockIdx.x * 256 + threadIdx.x;
    if (e >= N_EDGES) return;
    int s = src[e], d = dst[e];
    int pos = atomicAdd(&cursor[d], 1);
    csr_src[pos] = s;
    csr_norm[pos] = dis[s] * dis[d];
}

// ---------------------------------------------------------------- pack W2/W3 to B-frag order (device fn)
__device__ __forceinline__ void pack_one(const float* __restrict__ W, unsigned short* __restrict__ out,
                                         int idx, int N) {
    int lane = idx & 63;
    int ks = (idx >> 6) & 3;
    int ct = idx >> 8;
    int n = ct * 16 + (lane & 15);
    int kbase = ks * 32 + (lane >> 4) * 8;
    #pragma unroll
    for (int j = 0; j < 8; ++j)
        out[(size_t)idx * 8 + j] = f2bf(W[(size_t)(kbase + j) * N + n]);
}

// ---------------------------------------------------------------- layer 1 fused: agg(F=3) + GEMM 3->128 + b1 + relu -> fp8
#define NB1 6250
__global__ __launch_bounds__(256) void k_node1(const float* __restrict__ x,
                                               const float* __restrict__ dis,
                                               const int* __restrict__ row_ptr,
                                               const int* __restrict__ csr_src,
                                               const float* __restrict__ csr_norm,
                                               const float* __restrict__ W1,
                                               const float* __restrict__ b1,
                                               unsigned char* __restrict__ out,
                                               const float* __restrict__ W2,
                                               const float* __restrict__ W3,
                                               unsigned short* __restrict__ Wp2,
                                               unsigned short* __restrict__ Wp3) {
    int tid = threadIdx.x;
    if (blockIdx.x >= NB1) {                         // weight-pack role
        int idx = (blockIdx.x - NB1) * 256 + tid;    // 12 blocks = 3072
        if (idx < 2048) pack_one(W2, Wp2, idx, 128);
        else if (idx < 3072) pack_one(W3, Wp3, idx - 2048, 64);
        return;
    }
    __shared__ float Ws[384];
    __shared__ float bs[128];
    for (int i = tid; i < 384; i += 256) Ws[i] = W1[i];
    if (tid < 128) bs[tid] = b1[tid];
    __syncthreads();
    int gw = (blockIdx.x * 256 + tid) >> 6;          // 25000 waves
    int lane = tid & 63;
    int sub = lane >> 4, l16 = lane & 15;
    int node = gw * 4 + sub;                         // 100000 = 25000*4 exact
    int beg = row_ptr[node], end = row_ptr[node + 1];
    float p0 = 0.f, p1 = 0.f, p2 = 0.f;
    for (int e = beg + l16; e < end; e += 16) {
        int s = csr_src[e];
        float n = csr_norm[e];
        p0 = fmaf(x[s * 3 + 0], n, p0);
        p1 = fmaf(x[s * 3 + 1], n, p1);
        p2 = fmaf(x[s * 3 + 2], n, p2);
    }
    #pragma unroll
    for (int m = 8; m > 0; m >>= 1) {                // butterfly within 16-lane group
        p0 += __shfl_xor(p0, m, 64);
        p1 += __shfl_xor(p1, m, 64);
        p2 += __shfl_xor(p2, m, 64);
    }
    float d = dis[node], s2 = d * d;
    float a0 = fmaf(x[node * 3 + 0], s2, p0);
    float a1 = fmaf(x[node * 3 + 1], s2, p1);
    float a2 = fmaf(x[node * 3 + 2], s2, p2);
    int f = l16 * 8;
    float v[8];
    #pragma unroll
    for (int j = 0; j < 8; ++j)
        v[j] = fmaxf(bs[f + j] + a0 * Ws[f + j] + a1 * Ws[128 + f + j] + a2 * Ws[256 + f + j], 0.f);
    *(uint2*)(out + (size_t)node * 128 + f) = pack_fp8x8(v);
}

// ---------------------------------------------------------------- layers 2+3 fused, 32-node blocks:
// agg(F=128 fp8): 8 lanes/node x 16B uint4 gathers -> 8 nodes/wave in ONE gather round.
// -> bf16 LDS -> MFMA GEMM2 (+b2, relu) -> LDS -> MFMA GEMM3 -> Q2 fp8.  100000 = 3125*32.
__global__ __launch_bounds__(256) void k_layer23(const unsigned char* __restrict__ h1,
                                                 const float* __restrict__ dis,
                                                 const int* __restrict__ row_ptr,
                                                 const int* __restrict__ csr_src,
                                                 const float* __restrict__ csr_norm,
                                                 const unsigned short* __restrict__ Wp2,
                                                 const float* __restrict__ b2,
                                                 const unsigned short* __restrict__ Wp3,
                                                 unsigned char* __restrict__ Q2f8) {
    __shared__ unsigned short Asb[32][136];   // aggregated h1 tile (bf16 for MFMA)
    __shared__ unsigned short Hsb[32][136];   // h2 tile
    int tid = threadIdx.x;
    int wave = tid >> 6, lane = tid & 63;
    int quad = lane >> 4, m16 = lane & 15;
    int base = blockIdx.x * 32;

    // ---- phase 1: 8 nodes/wave, 8 lanes/node, 16 feats/lane (16B gathers)
    {
        int sub = lane >> 3, l8 = lane & 7;
        int r = wave * 8 + sub;
        int node = base + r;
        int beg = row_ptr[node], end = row_ptr[node + 1];
        int idx[8]; float nn[8];
        #pragma unroll
        for (int u = 0; u < 8; ++u) {
            int ee = beg + u; int cl = ee < end ? ee : end - 1;
            idx[u] = csr_src[cl]; nn[u] = ee < end ? csr_norm[cl] : 0.0f;
        }
        float d = dis[node];
        uint4 self = *(const uint4*)(h1 + (size_t)node * 128 + l8 * 16);
        uint4 g[8];
        #pragma unroll
        for (int u = 0; u < 8; ++u)
            g[u] = *(const uint4*)(h1 + (size_t)idx[u] * 128 + l8 * 16);
        float a[16];
        init16_fp8(a, self, d * d);
        #pragma unroll
        for (int u = 0; u < 8; ++u) fma16_fp8(a, g[u], nn[u]);
        for (int e = beg + 8; e < end; e += 8) {       // rare remainder (P(deg>8)~15%)
            int idx2[8]; float nn2[8];
            #pragma unroll
            for (int u = 0; u < 8; ++u) {
                int ee = e + u; int cl = ee < end ? ee : end - 1;
                idx2[u] = csr_src[cl]; nn2[u] = ee < end ? csr_norm[cl] : 0.0f;
            }
            uint4 g2[8];
            #pragma unroll
            for (int u = 0; u < 8; ++u)
                g2[u] = *(const uint4*)(h1 + (size_t)idx2[u] * 128 + l8 * 16);
            #pragma unroll
            for (int u = 0; u < 8; ++u) fma16_fp8(a, g2[u], nn2[u]);
        }
        *(short8*)(&Asb[r][l8 * 16])     = pack8(a);      // bf16 into LDS for MFMA
        *(short8*)(&Asb[r][l8 * 16 + 8]) = pack8(a + 8);
    }
    __syncthreads();

    // ---- phase 2: 32x128 = Asb(32x128) @ Wp2(128x128), +b2, relu -> Hsb
    int mt = wave & 1;                 // row tile (16 rows)
    int ch = wave >> 1;                // column half (64 cols)
    {
        short8 af[4];
        #pragma unroll
        for (int ks = 0; ks < 4; ++ks)
            af[ks] = *(const short8*)(&Asb[mt * 16 + m16][ks * 32 + quad * 8]);
        floatx4 acc[4];
        #pragma unroll
        for (int ct = 0; ct < 4; ++ct) acc[ct] = (floatx4){0.f, 0.f, 0.f, 0.f};
        #pragma unroll
        for (int ct = 0; ct < 4; ++ct) {
            int gct = ch * 4 + ct;
            #pragma unroll
            for (int ks = 0; ks < 4; ++ks) {
                short8 bf = *(const short8*)(Wp2 + ((size_t)(gct * 4 + ks) * 64 + lane) * 8);
                acc[ct] = __builtin_amdgcn_mfma_f32_16x16x32_bf16(af[ks], bf, acc[ct], 0, 0, 0);
            }
        }
        #pragma unroll
        for (int ct = 0; ct < 4; ++ct) {
            int col = (ch * 4 + ct) * 16 + m16;
            float bv = b2[col];
            #pragma unroll
            for (int r = 0; r < 4; ++r) {
                int row = mt * 16 + quad * 4 + r;
                Hsb[row][col] = f2bf(fmaxf(acc[ct][r] + bv, 0.0f));
            }
        }
    }
    __syncthreads();

    // ---- phase 3: 32x64 = Hsb(32x128) @ Wp3(128x64) -> global Q2 (fp8, no bias)
    {
        int cp = wave >> 1;            // column pair (32 cols)
        short8 hf[4];
        #pragma unroll
        for (int ks = 0; ks < 4; ++ks)
            hf[ks] = *(const short8*)(&Hsb[mt * 16 + m16][ks * 32 + quad * 8]);
        floatx4 acc3[2];
        acc3[0] = (floatx4){0.f, 0.f, 0.f, 0.f};
        acc3[1] = (floatx4){0.f, 0.f, 0.f, 0.f};
        #pragma unroll
        for (int ct = 0; ct < 2; ++ct) {
            int gct = cp * 2 + ct;
            #pragma unroll
            for (int ks = 0; ks < 4; ++ks) {
                short8 bf = *(const short8*)(Wp3 + ((size_t)(gct * 4 + ks) * 64 + lane) * 8);
                acc3[ct] = __builtin_amdgcn_mfma_f32_16x16x32_bf16(hf[ks], bf, acc3[ct], 0, 0, 0);
            }
        }
        #pragma unroll
        for (int ct = 0; ct < 2; ++ct) {
            int col = (cp * 2 + ct) * 16 + m16;
            #pragma unroll
            for (int r = 0; r < 4; ++r) {
                long row = base + mt * 16 + quad * 4 + r;
                Q2f8[row * 64 + col] = f2fp8(acc3[ct][r]);
            }
        }
    }
}

// ---------------------------------------------------------------- aggregation F=64 fp8 (row = 64B = ONE line)
// + bias + relu + Wl dot. 16 nodes/wave: 4 lanes x 16 feats (16B uint4 gathers), single gather round.
__global__ __launch_bounds__(256) void k_agg64_dot(const unsigned char* __restrict__ h,
                                                   const float* __restrict__ dis,
                                                   const int* __restrict__ row_ptr,
                                                   const int* __restrict__ csr_src,
                                                   const float* __restrict__ csr_norm,
                                                   const float* __restrict__ bias,
                                                   const float* __restrict__ Wl,
                                                   float* __restrict__ s_out) {
    int gw = (blockIdx.x * 256 + threadIdx.x) >> 6;  // 6250 waves of work
    if (gw >= N_NODES / 16) return;                  // 100000 = 6250*16
    int lane = threadIdx.x & 63;
    int sub = lane >> 2, l4 = lane & 3;
    int node = gw * 16 + sub;
    int beg = row_ptr[node], end = row_ptr[node + 1];
    int idx[8]; float nn[8];
    #pragma unroll
    for (int u = 0; u < 8; ++u) {
        int ee = beg + u; int cl = ee < end ? ee : end - 1;
        idx[u] = csr_src[cl]; nn[u] = ee < end ? csr_norm[cl] : 0.0f;
    }
    float d = dis[node];
    uint4 self = *(const uint4*)(h + (size_t)node * 64 + l4 * 16);
    uint4 g[8];
    #pragma unroll
    for (int u = 0; u < 8; ++u)
        g[u] = *(const uint4*)(h + (size_t)idx[u] * 64 + l4 * 16);
    float a[16];
    init16_fp8(a, self, d * d);
    #pragma unroll
    for (int u = 0; u < 8; ++u) fma16_fp8(a, g[u], nn[u]);
    for (int e = beg + 8; e < end; e += 8) {         // rare remainder
        int idx2[8]; float nn2[8];
        #pragma unroll
        for (int u = 0; u < 8; ++u) {
            int ee = e + u; int cl = ee < end ? ee : end - 1;
            idx2[u] = csr_src[cl]; nn2[u] = ee < end ? csr_norm[cl] : 0.0f;
        }
        uint4 g2[8];
        #pragma unroll
        for (int u = 0; u < 8; ++u)
            g2[u] = *(const uint4*)(h + (size_t)idx2[u] * 64 + l4 * 16);
        #pragma unroll
        for (int u = 0; u < 8; ++u) fma16_fp8(a, g2[u], nn2[u]);
    }
    int f = l4 * 16;
    float v = 0.f;
    #pragma unroll
    for (int j = 0; j < 16; ++j)
        v = fmaf(fmaxf(a[j] + bias[f + j], 0.f), Wl[f + j], v);
    v += __shfl_xor(v, 1, 64);                       // reduce within 4-lane group
    v += __shfl_xor(v, 2, 64);
    if (l4 == 0) s_out[node] = v;
}

// ---------------------------------------------------------------- pool over per-node scalars
__global__ __launch_bounds__(256) void k_pool2(const float* __restrict__ s,
                                               const int* __restrict__ batch,
                                               const float* __restrict__ bl,
                                               float* __restrict__ out) {
    int g = blockIdx.x;
    int tid = threadIdx.x;
    int lo = 0, hi = N_NODES;
    while (lo < hi) { int m = (lo + hi) >> 1; if (batch[m] < g) lo = m + 1; else hi = m; }
    int lo2 = lo, hi2 = N_NODES;
    while (lo2 < hi2) { int m = (lo2 + hi2) >> 1; if (batch[m] < g + 1) lo2 = m + 1; else hi2 = m; }
    float acc = 0.0f;
    for (int n = lo + tid; n < lo2; n += 256) acc += s[n];
    __shared__ float sm[256];
    sm[tid] = acc; __syncthreads();
    for (int off = 128; off > 0; off >>= 1) {
        if (tid < off) sm[tid] += sm[tid + off];
        __syncthreads();
    }
    if (tid == 0) out[g] = sm[0] / fmaxf((float)(lo2 - lo), 1.0f) + bl[0];
}

// ---------------------------------------------------------------- launcher
extern "C" void kernel_launch(void* const* d_in, const int* in_sizes, int n_in,
                              void* d_out, int out_size, void* d_ws, size_t ws_size,
                              hipStream_t stream) {
    const float* x     = (const float*)d_in[0];
    const int*   ei    = (const int*)d_in[1];     // [0..E) = src, [E..2E) = dst
    const int*   batch = (const int*)d_in[2];
    const float* W1 = (const float*)d_in[3];
    const float* b1 = (const float*)d_in[4];
    const float* W2 = (const float*)d_in[5];
    const float* b2 = (const float*)d_in[6];
    const float* W3 = (const float*)d_in[7];
    const float* b3 = (const float*)d_in[8];
    const float* Wl = (const float*)d_in[9];
    const float* bl = (const float*)d_in[10];
    float* out = (float*)d_out;

    const int* e_src = ei;
    const int* e_dst = ei + N_EDGES;

    char* ws = (char*)d_ws;
    size_t off = 0;
    auto alloc = [&](size_t bytes) -> char* {
        char* p = ws + off;
        off = (off + bytes + 255) & ~(size_t)255;
        return p;
    };
    int*   cnt      = (int*)  alloc((size_t)N_NODES * 4);
    float* dis      = (float*)alloc((size_t)N_NODES * 4);
    int*   row_ptr  = (int*)  alloc((size_t)(N_NODES + 1) * 4);
    int*   cursor   = (int*)  alloc((size_t)N_NODES * 4);
    int*   part     = (int*)  alloc(1024 * 4);
    int*   csr_src  = (int*)  alloc((size_t)N_EDGES * 4);
    float* csr_norm = (float*)alloc((size_t)N_EDGES * 4);
    float* nscal    = (float*)alloc((size_t)N_NODES * 4);
    unsigned char*  P1f8 = (unsigned char*) alloc((size_t)N_NODES * 128);    // h1 fp8 (128B/row, 2 lines)
    unsigned char*  Q2f8 = (unsigned char*) alloc((size_t)N_NODES * 64);     // h2@W3 fp8 (64B/row, 1 line)
    unsigned short* Wp2  = (unsigned short*)alloc((size_t)128 * 128 * 2);
    unsigned short* Wp3  = (unsigned short*)alloc((size_t)128 * 64 * 2);

    const int NB_N = (N_NODES + 255) / 256;   // 391
    const int NB_E = (N_EDGES + 255) / 256;

    hipMemsetAsync(cnt, 0, (size_t)N_NODES * 4, stream);
    k_hist<<<NB_E, 256, 0, stream>>>(e_dst, cnt);
    k_scan1<<<NB_N, 256, 0, stream>>>(cnt, part);
    k_scan3<<<NB_N, 256, 0, stream>>>(cnt, part, row_ptr, cursor, dis);
    k_scatter<<<NB_E, 256, 0, stream>>>(e_src, e_dst, dis, cursor, csr_src, csr_norm);

    // layer 1 fused: agg(F=3) + GEMM 3->128 + b1 + relu -> fp8 (+12 pack blocks)
    k_node1<<<NB1 + 12, 256, 0, stream>>>(x, dis, row_ptr, csr_src, csr_norm,
                                          W1, b1, P1f8, W2, W3, Wp2, Wp3);

    // layers 2+3 fused (32-node blocks, 8 nodes/wave): agg(F=128 fp8) + GEMM2 + GEMM3 -> Q2 fp8
    k_layer23<<<N_NODES / 32, 256, 0, stream>>>(P1f8, dis, row_ptr, csr_src, csr_norm,
                                                Wp2, b2, Wp3, Q2f8);

    // layer 3 aggregation (fp8 rows = 1 line, 16 nodes/wave) + b3 + relu + dot(Wl)
    k_agg64_dot<<<(N_NODES / 16 + 3) / 4, 256, 0, stream>>>(Q2f8, dis, row_ptr, csr_src, csr_norm,
                                                            b3, Wl, nscal);

    // mean pool (+ bl) over per-node scalars
    k_pool2<<<N_GRAPHS, 256, 0, stream>>>(nscal, batch, bl, out);
}